// Round 2
// baseline (408.191 us; speedup 1.0000x reference)
//
#include <hip/hip_runtime.h>

typedef unsigned short u16;
typedef __bf16 bf16x8 __attribute__((ext_vector_type(8)));
typedef float f32x4 __attribute__((ext_vector_type(4)));
typedef unsigned short u16x4 __attribute__((ext_vector_type(4)));

#define MFMA_B16(a, b, c) __builtin_amdgcn_mfma_f32_16x16x32_bf16((a), (b), (c), 0, 0, 0)

// ---------- helpers ----------
__device__ __forceinline__ u16 f2bf(float f) {
  unsigned int u = __float_as_uint(f);
  u += 0x7FFFu + ((u >> 16) & 1u);   // RNE
  return (u16)(u >> 16);
}

__device__ __forceinline__ u16x4 f4_to_bf4(float4 v) {
  u16x4 r;
  r[0] = f2bf(v.x); r[1] = f2bf(v.y); r[2] = f2bf(v.z); r[3] = f2bf(v.w);
  return r;
}

// ---------- f32 -> bf16 converts ----------
__global__ __launch_bounds__(256) void cvt3(const float* __restrict__ a,
                                            const float* __restrict__ b,
                                            const float* __restrict__ c,
                                            u16* __restrict__ dst, int n4, int n) {
  int i = blockIdx.x * 256 + threadIdx.x;
  int stride = gridDim.x * 256;
  const float4* a4 = (const float4*)a;
  const float4* b4 = (const float4*)b;
  const float4* c4 = (const float4*)c;
  u16x4* d0 = (u16x4*)dst;
  u16x4* d1 = (u16x4*)(dst + (size_t)n);
  u16x4* d2 = (u16x4*)(dst + (size_t)2 * n);
  for (; i < n4; i += stride) {
    d0[i] = f4_to_bf4(a4[i]);
    d1[i] = f4_to_bf4(b4[i]);
    d2[i] = f4_to_bf4(c4[i]);
  }
}

__global__ __launch_bounds__(256) void cvtW(const float* __restrict__ a,
                                            const float* __restrict__ b,
                                            const float* __restrict__ c,
                                            const float* __restrict__ d,
                                            u16* __restrict__ dst, int n4, int n) {
  int i = blockIdx.x * 256 + threadIdx.x;
  int stride = gridDim.x * 256;
  const float4* a4 = (const float4*)a;
  const float4* b4 = (const float4*)b;
  const float4* c4 = (const float4*)c;
  const float4* d4 = (const float4*)d;
  u16x4* o0 = (u16x4*)dst;
  u16x4* o1 = (u16x4*)(dst + (size_t)n);
  u16x4* o2 = (u16x4*)(dst + (size_t)2 * n);
  u16x4* o3 = (u16x4*)(dst + (size_t)3 * n);
  for (; i < n4; i += stride) {
    o0[i] = f4_to_bf4(a4[i]);
    o1[i] = f4_to_bf4(b4[i]);
    o2[i] = f4_to_bf4(c4[i]);
    o3[i] = f4_to_bf4(d4[i]);
  }
}

// ---------- B-transposed bf16 GEMM: C[M,512] = A[M,512] * Bw[512,512]^T ----------
// 128x128 tile, 4 waves (2x2 of 64x64), BK=32, N=K=512 hardcoded.
template <bool OUT_F32>
__device__ __forceinline__ void gemm_body(const u16* __restrict__ A,
                                          const u16* __restrict__ Bw,
                                          u16* __restrict__ Cb, float* __restrict__ Cf,
                                          int bm, int bn) {
  __shared__ __align__(16) u16 As[128][40];
  __shared__ __align__(16) u16 Bs[128][40];
  const int tid = threadIdx.x;
  const int wave = tid >> 6, lane = tid & 63;
  const int g = lane >> 4, l16 = lane & 15;
  const int wr = (wave >> 1) * 64, wc = (wave & 1) * 64;
  const int srow = tid >> 1, scol = (tid & 1) * 16;  // each thread: 16 contiguous u16
  const u16* Ar = A + (size_t)(bm + srow) * 512 + scol;
  const u16* Br = Bw + (size_t)(bn + srow) * 512 + scol;
  f32x4 acc[4][4] = {};
  for (int k0 = 0; k0 < 512; k0 += 32) {
    // 2 x uint4 (= 16 u16) per thread: full 128x32 tile coverage
    *(uint4*)(&As[srow][scol])     = *(const uint4*)(Ar + k0);
    *(uint4*)(&As[srow][scol + 8]) = *(const uint4*)(Ar + k0 + 8);
    *(uint4*)(&Bs[srow][scol])     = *(const uint4*)(Br + k0);
    *(uint4*)(&Bs[srow][scol + 8]) = *(const uint4*)(Br + k0 + 8);
    __syncthreads();
    bf16x8 af[4], bfr[4];
#pragma unroll
    for (int i = 0; i < 4; ++i) af[i] = *(const bf16x8*)(&As[wr + i * 16 + l16][g * 8]);
#pragma unroll
    for (int j = 0; j < 4; ++j) bfr[j] = *(const bf16x8*)(&Bs[wc + j * 16 + l16][g * 8]);
#pragma unroll
    for (int i = 0; i < 4; ++i)
#pragma unroll
      for (int j = 0; j < 4; ++j)
        acc[i][j] = MFMA_B16(af[i], bfr[j], acc[i][j]);
    __syncthreads();
  }
#pragma unroll
  for (int i = 0; i < 4; ++i)
#pragma unroll
    for (int j = 0; j < 4; ++j)
#pragma unroll
      for (int r = 0; r < 4; ++r) {
        int row = bm + wr + i * 16 + g * 4 + r;   // C row = (lane>>4)*4 + reg  [m89]
        int col = bn + wc + j * 16 + l16;         // C col = lane&15
        if constexpr (OUT_F32)
          Cf[(size_t)row * 512 + col] = acc[i][j][r];
        else
          Cb[(size_t)row * 512 + col] = f2bf(acc[i][j][r]);
      }
}

__global__ __launch_bounds__(256) void gemm_qkv(const u16* __restrict__ Xbf,
                                                const u16* __restrict__ Wbf,
                                                u16* __restrict__ QKVp) {
  int z = blockIdx.z;
  gemm_body<false>(Xbf + (size_t)z * 4194304, Wbf + (size_t)z * 262144,
                   QKVp + (size_t)z * 4194304, nullptr,
                   blockIdx.x * 128, blockIdx.y * 128);
}

__global__ __launch_bounds__(256) void gemm_f32out(const u16* __restrict__ A,
                                                   const u16* __restrict__ Bw,
                                                   float* __restrict__ C) {
  gemm_body<true>(A, Bw, nullptr, C, blockIdx.x * 128, blockIdx.y * 128);
}

// ---------- V transpose: Vp[b][s][d] (bf16) -> Vt[b][d][s] (bf16) ----------
__global__ __launch_bounds__(256) void transpose_v(const u16* __restrict__ Vp,
                                                   u16* __restrict__ Vt) {
  __shared__ __align__(16) u16 t[64][72];
  const int b = blockIdx.z;
  const int s0 = blockIdx.x * 64, d0 = blockIdx.y * 64;
  const u16* in = Vp + (size_t)b * 2048 * 512;
  u16* outp = Vt + (size_t)b * 512 * 2048;
  const int tid = threadIdx.x;
  const int r = tid >> 2;           // 0..63
  const int c = (tid & 3) * 16;     // 0,16,32,48
  const uint4* src = (const uint4*)(in + (size_t)(s0 + r) * 512 + d0 + c);
  uint4 v0 = src[0], v1 = src[1];
  *(uint4*)(&t[r][c]) = v0;
  *(uint4*)(&t[r][c + 8]) = v1;
  __syncthreads();
  u16 tmp[16];
#pragma unroll
  for (int j = 0; j < 16; ++j) tmp[j] = t[c + j][r];
  uint4* dst = (uint4*)(outp + (size_t)(d0 + r) * 2048 + s0 + c);
  dst[0] = *(uint4*)(&tmp[0]);
  dst[1] = *(uint4*)(&tmp[8]);
}

// ---------- fused causal attention ----------
// grid (16 qtiles, 32 bh); block 256 = 4 waves, each wave owns 32 q-rows.
// Pass A: online (m,l) over k-tiles.  Pass B: recompute S, write attn (f32),
// P->LDS (bf16) -> PV MFMA.  Tail columns zero-filled.
__global__ __launch_bounds__(256) void attn_kernel(const u16* __restrict__ Qp,
                                                   const u16* __restrict__ Kp,
                                                   const u16* __restrict__ Vt,
                                                   float* __restrict__ attn_all,
                                                   u16* __restrict__ ctx) {
  __shared__ __align__(16) u16 Plds[4][32][136];
  const int tid = threadIdx.x;
  const int wave = tid >> 6, lane = tid & 63;
  const int g = lane >> 4, l16 = lane & 15;
  const int qt = blockIdx.x, bh = blockIdx.y;
  const int b = bh >> 3, h = bh & 7;
  const int q0 = qt * 128;
  const int wq = q0 + wave * 32;
  const u16* Qh = Qp + ((size_t)b * 2048) * 512 + h * 64;
  const u16* Kh = Kp + ((size_t)b * 2048) * 512 + h * 64;
  const u16* Vh = Vt + ((size_t)b * 512 + h * 64) * 2048;
  float* attn = attn_all + (size_t)bh * 2048 * 2048;

  // Q fragments for this wave's 32 rows (A-operand: row=lane&15, k=(lane>>4)*8+j)
  bf16x8 qf[2][2];
#pragma unroll
  for (int fr = 0; fr < 2; ++fr)
#pragma unroll
    for (int kb = 0; kb < 2; ++kb)
      qf[fr][kb] = *(const bf16x8*)(Qh + (size_t)(wq + fr * 16 + l16) * 512 + kb * 32 + g * 8);

  float m[2][4], l[2][4];
#pragma unroll
  for (int fr = 0; fr < 2; ++fr)
#pragma unroll
    for (int r = 0; r < 4; ++r) { m[fr][r] = -1e30f; l[fr][r] = 0.f; }

  const int nkt = qt + 1;

  // ---- Pass A: row max & sum ----
  for (int kt = 0; kt < nkt; ++kt) {
    float s[2][8][4];
#pragma unroll
    for (int cf = 0; cf < 8; ++cf) {
      const u16* Krow = Kh + (size_t)(kt * 128 + cf * 16 + l16) * 512;
      bf16x8 b0 = *(const bf16x8*)(Krow + g * 8);
      bf16x8 b1 = *(const bf16x8*)(Krow + 32 + g * 8);
#pragma unroll
      for (int fr = 0; fr < 2; ++fr) {
        f32x4 cacc = {0.f, 0.f, 0.f, 0.f};
        cacc = MFMA_B16(qf[fr][0], b0, cacc);
        cacc = MFMA_B16(qf[fr][1], b1, cacc);
#pragma unroll
        for (int r = 0; r < 4; ++r) {
          int q = wq + fr * 16 + g * 4 + r;
          int kk = kt * 128 + cf * 16 + l16;
          s[fr][cf][r] = (kk > q) ? -1e30f : cacc[r] * 0.125f;
        }
      }
    }
#pragma unroll
    for (int fr = 0; fr < 2; ++fr)
#pragma unroll
      for (int r = 0; r < 4; ++r) {
        float pm = s[fr][0][r];
#pragma unroll
        for (int cf = 1; cf < 8; ++cf) pm = fmaxf(pm, s[fr][cf][r]);
#pragma unroll
        for (int d = 1; d < 16; d <<= 1) pm = fmaxf(pm, __shfl_xor(pm, d));
        float mn = fmaxf(m[fr][r], pm);
        float ps = 0.f;
#pragma unroll
        for (int cf = 0; cf < 8; ++cf) ps += __expf(s[fr][cf][r] - mn);
#pragma unroll
        for (int d = 1; d < 16; d <<= 1) ps += __shfl_xor(ps, d);
        l[fr][r] = l[fr][r] * __expf(m[fr][r] - mn) + ps;
        m[fr][r] = mn;
      }
  }

  float invl[2][4];
#pragma unroll
  for (int fr = 0; fr < 2; ++fr)
#pragma unroll
    for (int r = 0; r < 4; ++r) invl[fr][r] = 1.f / l[fr][r];

  // ---- Pass B: write attn + PV ----
  f32x4 oacc[2][4] = {};
  for (int kt = 0; kt < nkt; ++kt) {
#pragma unroll
    for (int cf = 0; cf < 8; ++cf) {
      const u16* Krow = Kh + (size_t)(kt * 128 + cf * 16 + l16) * 512;
      bf16x8 b0 = *(const bf16x8*)(Krow + g * 8);
      bf16x8 b1 = *(const bf16x8*)(Krow + 32 + g * 8);
#pragma unroll
      for (int fr = 0; fr < 2; ++fr) {
        f32x4 cacc = {0.f, 0.f, 0.f, 0.f};
        cacc = MFMA_B16(qf[fr][0], b0, cacc);
        cacc = MFMA_B16(qf[fr][1], b1, cacc);
#pragma unroll
        for (int r = 0; r < 4; ++r) {
          int q = wq + fr * 16 + g * 4 + r;
          int kk = kt * 128 + cf * 16 + l16;
          float p = (kk > q) ? 0.f : __expf(cacc[r] * 0.125f - m[fr][r]) * invl[fr][r];
          attn[(size_t)q * 2048 + kk] = p;
          Plds[wave][fr * 16 + g * 4 + r][cf * 16 + l16] = f2bf(p);
        }
      }
    }
    __syncthreads();
#pragma unroll
    for (int kb = 0; kb < 4; ++kb) {
      bf16x8 pa[2];
#pragma unroll
      for (int fr = 0; fr < 2; ++fr)
        pa[fr] = *(const bf16x8*)(&Plds[wave][fr * 16 + l16][kb * 32 + g * 8]);
#pragma unroll
      for (int cn = 0; cn < 4; ++cn) {
        bf16x8 vb = *(const bf16x8*)(Vh + (size_t)(cn * 16 + l16) * 2048 + kt * 128 + kb * 32 + g * 8);
#pragma unroll
        for (int fr = 0; fr < 2; ++fr)
          oacc[fr][cn] = MFMA_B16(pa[fr], vb, oacc[fr][cn]);
      }
    }
    __syncthreads();
  }

  // ctx write: [B,S,D] bf16, col = h*64 + d
  u16* cb = ctx + ((size_t)b * 2048) * 512 + h * 64;
#pragma unroll
  for (int fr = 0; fr < 2; ++fr)
#pragma unroll
    for (int cn = 0; cn < 4; ++cn)
#pragma unroll
      for (int r = 0; r < 4; ++r)
        cb[(size_t)(wq + fr * 16 + g * 4 + r) * 512 + cn * 16 + l16] = f2bf(oacc[fr][cn][r]);

  // zero fill strictly-upper tail columns
  const int z0 = nkt * 128;
  const int zw = 2048 - z0;
  if (zw > 0) {
    const int cpr = zw >> 2;
    const int total = 128 * cpr;
    float4 z4 = make_float4(0.f, 0.f, 0.f, 0.f);
    for (int idx = tid; idx < total; idx += 256) {
      int r = idx / cpr;
      int c = (idx - r * cpr) * 4;
      *(float4*)(&attn[(size_t)(q0 + r) * 2048 + z0 + c]) = z4;
    }
  }
}

// ---------- residual + LayerNorm ----------
__global__ __launch_bounds__(256) void ln_kernel(const float* __restrict__ proj,
                                                 const float* __restrict__ resid,
                                                 const float* __restrict__ gamma,
                                                 const float* __restrict__ beta,
                                                 float* __restrict__ out) {
  const int wave = threadIdx.x >> 6, lane = threadIdx.x & 63;
  const int row = blockIdx.x * 4 + wave;
  const float4* p4 = (const float4*)(proj + (size_t)row * 512);
  const float4* r4 = (const float4*)(resid + (size_t)row * 512);
  float4 a0 = p4[lane * 2], a1 = p4[lane * 2 + 1];
  float4 q0 = r4[lane * 2], q1 = r4[lane * 2 + 1];
  float x[8];
  x[0] = a0.x + q0.x; x[1] = a0.y + q0.y; x[2] = a0.z + q0.z; x[3] = a0.w + q0.w;
  x[4] = a1.x + q1.x; x[5] = a1.y + q1.y; x[6] = a1.z + q1.z; x[7] = a1.w + q1.w;
  float s = 0.f;
#pragma unroll
  for (int j = 0; j < 8; ++j) s += x[j];
#pragma unroll
  for (int d = 1; d < 64; d <<= 1) s += __shfl_xor(s, d);
  float mu = s * (1.f / 512.f);
  float v = 0.f;
#pragma unroll
  for (int j = 0; j < 8; ++j) { float t = x[j] - mu; v += t * t; }
#pragma unroll
  for (int d = 1; d < 64; d <<= 1) v += __shfl_xor(v, d);
  float rs = rsqrtf(v * (1.f / 512.f) + 1e-5f);
  const float4* g4 = (const float4*)gamma;
  const float4* b4 = (const float4*)beta;
  float4 g0 = g4[lane * 2], g1 = g4[lane * 2 + 1];
  float4 bb0 = b4[lane * 2], bb1 = b4[lane * 2 + 1];
  float4 y0, y1;
  y0.x = (x[0] - mu) * rs * g0.x + bb0.x;
  y0.y = (x[1] - mu) * rs * g0.y + bb0.y;
  y0.z = (x[2] - mu) * rs * g0.z + bb0.z;
  y0.w = (x[3] - mu) * rs * g0.w + bb0.w;
  y1.x = (x[4] - mu) * rs * g1.x + bb1.x;
  y1.y = (x[5] - mu) * rs * g1.y + bb1.y;
  y1.z = (x[6] - mu) * rs * g1.z + bb1.z;
  y1.w = (x[7] - mu) * rs * g1.w + bb1.w;
  float4* o4 = (float4*)(out + (size_t)row * 512);
  o4[lane * 2] = y0;
  o4[lane * 2 + 1] = y1;
}

// ---------- launch ----------
extern "C" void kernel_launch(void* const* d_in, const int* in_sizes, int n_in,
                              void* d_out, int out_size, void* d_ws, size_t ws_size,
                              hipStream_t stream) {
  (void)in_sizes; (void)n_in; (void)out_size; (void)ws_size;
  const float* inQ = (const float*)d_in[0];
  const float* inK = (const float*)d_in[1];
  const float* inV = (const float*)d_in[2];
  // d_in[3] = attn_mask (causal by construction; applied analytically)
  const float* Wq = (const float*)d_in[4];
  const float* Wk = (const float*)d_in[5];
  const float* Wv = (const float*)d_in[6];
  const float* Wo = (const float*)d_in[7];
  const float* gamma = (const float*)d_in[8];
  const float* beta = (const float*)d_in[9];

  float* out = (float*)d_out;
  float* attn = out + (size_t)4 * 2048 * 512;        // 4,194,304 floats

  char* ws = (char*)d_ws;
  u16* Qp  = (u16*)(ws + 0);            // 8,388,608 B
  u16* Kp  = (u16*)(ws + 8388608);      // 8,388,608 B
  u16* Vp  = (u16*)(ws + 16777216);     // 8,388,608 B
  u16* Vt  = (u16*)(ws + 25165824);     // 8,388,608 B
  u16* ctx = (u16*)(ws + 33554432);     // 8,388,608 B
  u16* Wbf = (u16*)(ws + 41943040);     // 2,097,152 B  (total ws: 44,040,192 B)
  float* proj = (float*)(ws + 0);       // reuses Qp+Kp after attention is done
  u16* Xbf = (u16*)attn;                // 25 MB scratch in attn region (pre-attention)

  cvt3<<<2048, 256, 0, stream>>>(inQ, inK, inV, Xbf, 1048576, 4194304);
  cvtW<<<256, 256, 0, stream>>>(Wq, Wk, Wv, Wo, Wbf, 65536, 262144);
  gemm_qkv<<<dim3(64, 4, 3), 256, 0, stream>>>(Xbf, Wbf, Qp);
  transpose_v<<<dim3(32, 8, 4), 256, 0, stream>>>(Vp, Vt);
  attn_kernel<<<dim3(16, 32), 256, 0, stream>>>(Qp, Kp, Vt, attn, ctx);
  gemm_f32out<<<dim3(64, 4, 1), 256, 0, stream>>>(ctx, Wbf + (size_t)3 * 262144, proj);
  ln_kernel<<<2048, 256, 0, stream>>>(proj, inQ, gamma, beta, out);
}

// Round 3
// 402.280 us; speedup vs baseline: 1.0147x; 1.0147x over previous
//
#include <hip/hip_runtime.h>

typedef unsigned short u16;
typedef __bf16 bf16x8 __attribute__((ext_vector_type(8)));
typedef float f32x4 __attribute__((ext_vector_type(4)));
typedef unsigned short u16x4 __attribute__((ext_vector_type(4)));

#define MFMA_B16(a, b, c) __builtin_amdgcn_mfma_f32_16x16x32_bf16((a), (b), (c), 0, 0, 0)

// ---------- helpers ----------
__device__ __forceinline__ u16 f2bf(float f) {
  unsigned int u = __float_as_uint(f);
  u += 0x7FFFu + ((u >> 16) & 1u);   // RNE
  return (u16)(u >> 16);
}

__device__ __forceinline__ u16x4 f4_to_bf4(float4 v) {
  u16x4 r;
  r[0] = f2bf(v.x); r[1] = f2bf(v.y); r[2] = f2bf(v.z); r[3] = f2bf(v.w);
  return r;
}

// ---------- f32 -> bf16 converts ----------
__global__ __launch_bounds__(256) void cvt3(const float* __restrict__ a,
                                            const float* __restrict__ b,
                                            const float* __restrict__ c,
                                            u16* __restrict__ dst, int n4, int n) {
  int i = blockIdx.x * 256 + threadIdx.x;
  int stride = gridDim.x * 256;
  const float4* a4 = (const float4*)a;
  const float4* b4 = (const float4*)b;
  const float4* c4 = (const float4*)c;
  u16x4* d0 = (u16x4*)dst;
  u16x4* d1 = (u16x4*)(dst + (size_t)n);
  u16x4* d2 = (u16x4*)(dst + (size_t)2 * n);
  for (; i < n4; i += stride) {
    d0[i] = f4_to_bf4(a4[i]);
    d1[i] = f4_to_bf4(b4[i]);
    d2[i] = f4_to_bf4(c4[i]);
  }
}

__global__ __launch_bounds__(256) void cvtW(const float* __restrict__ a,
                                            const float* __restrict__ b,
                                            const float* __restrict__ c,
                                            const float* __restrict__ d,
                                            u16* __restrict__ dst, int n4, int n) {
  int i = blockIdx.x * 256 + threadIdx.x;
  int stride = gridDim.x * 256;
  const float4* a4 = (const float4*)a;
  const float4* b4 = (const float4*)b;
  const float4* c4 = (const float4*)c;
  const float4* d4 = (const float4*)d;
  u16x4* o0 = (u16x4*)dst;
  u16x4* o1 = (u16x4*)(dst + (size_t)n);
  u16x4* o2 = (u16x4*)(dst + (size_t)2 * n);
  u16x4* o3 = (u16x4*)(dst + (size_t)3 * n);
  for (; i < n4; i += stride) {
    o0[i] = f4_to_bf4(a4[i]);
    o1[i] = f4_to_bf4(b4[i]);
    o2[i] = f4_to_bf4(c4[i]);
    o3[i] = f4_to_bf4(d4[i]);
  }
}

// ---------- B-transposed bf16 GEMM: C[M,512] = A[M,512] * Bw[512,512]^T ----------
template <bool OUT_F32>
__device__ __forceinline__ void gemm_body(const u16* __restrict__ A,
                                          const u16* __restrict__ Bw,
                                          u16* __restrict__ Cb, float* __restrict__ Cf,
                                          int bm, int bn) {
  __shared__ __align__(16) u16 As[128][40];
  __shared__ __align__(16) u16 Bs[128][40];
  const int tid = threadIdx.x;
  const int wave = tid >> 6, lane = tid & 63;
  const int g = lane >> 4, l16 = lane & 15;
  const int wr = (wave >> 1) * 64, wc = (wave & 1) * 64;
  const int srow = tid >> 1, scol = (tid & 1) * 16;
  const u16* Ar = A + (size_t)(bm + srow) * 512 + scol;
  const u16* Br = Bw + (size_t)(bn + srow) * 512 + scol;
  f32x4 acc[4][4] = {};
  for (int k0 = 0; k0 < 512; k0 += 32) {
    *(uint4*)(&As[srow][scol])     = *(const uint4*)(Ar + k0);
    *(uint4*)(&As[srow][scol + 8]) = *(const uint4*)(Ar + k0 + 8);
    *(uint4*)(&Bs[srow][scol])     = *(const uint4*)(Br + k0);
    *(uint4*)(&Bs[srow][scol + 8]) = *(const uint4*)(Br + k0 + 8);
    __syncthreads();
    bf16x8 af[4], bfr[4];
#pragma unroll
    for (int i = 0; i < 4; ++i) af[i] = *(const bf16x8*)(&As[wr + i * 16 + l16][g * 8]);
#pragma unroll
    for (int j = 0; j < 4; ++j) bfr[j] = *(const bf16x8*)(&Bs[wc + j * 16 + l16][g * 8]);
#pragma unroll
    for (int i = 0; i < 4; ++i)
#pragma unroll
      for (int j = 0; j < 4; ++j)
        acc[i][j] = MFMA_B16(af[i], bfr[j], acc[i][j]);
    __syncthreads();
  }
#pragma unroll
  for (int i = 0; i < 4; ++i)
#pragma unroll
    for (int j = 0; j < 4; ++j)
#pragma unroll
      for (int r = 0; r < 4; ++r) {
        int row = bm + wr + i * 16 + g * 4 + r;
        int col = bn + wc + j * 16 + l16;
        if constexpr (OUT_F32)
          Cf[(size_t)row * 512 + col] = acc[i][j][r];
        else
          Cb[(size_t)row * 512 + col] = f2bf(acc[i][j][r]);
      }
}

__global__ __launch_bounds__(256) void gemm_qkv(const u16* __restrict__ Xbf,
                                                const u16* __restrict__ Wbf,
                                                u16* __restrict__ QKVp) {
  int z = blockIdx.z;
  gemm_body<false>(Xbf + (size_t)z * 4194304, Wbf + (size_t)z * 262144,
                   QKVp + (size_t)z * 4194304, nullptr,
                   blockIdx.x * 128, blockIdx.y * 128);
}

__global__ __launch_bounds__(256) void gemm_f32out(const u16* __restrict__ A,
                                                   const u16* __restrict__ Bw,
                                                   float* __restrict__ C) {
  gemm_body<true>(A, Bw, nullptr, C, blockIdx.x * 128, blockIdx.y * 128);
}

// ---------- V transpose: Vp[b][s][d] (bf16) -> Vt[b][d][s] (bf16) ----------
__global__ __launch_bounds__(256) void transpose_v(const u16* __restrict__ Vp,
                                                   u16* __restrict__ Vt) {
  __shared__ __align__(16) u16 t[64][72];
  const int b = blockIdx.z;
  const int s0 = blockIdx.x * 64, d0 = blockIdx.y * 64;
  const u16* in = Vp + (size_t)b * 2048 * 512;
  u16* outp = Vt + (size_t)b * 512 * 2048;
  const int tid = threadIdx.x;
  const int r = tid >> 2;
  const int c = (tid & 3) * 16;
  const uint4* src = (const uint4*)(in + (size_t)(s0 + r) * 512 + d0 + c);
  uint4 v0 = src[0], v1 = src[1];
  *(uint4*)(&t[r][c]) = v0;
  *(uint4*)(&t[r][c + 8]) = v1;
  __syncthreads();
  u16 tmp[16];
#pragma unroll
  for (int j = 0; j < 16; ++j) tmp[j] = t[c + j][r];
  uint4* dst = (uint4*)(outp + (size_t)(d0 + r) * 2048 + s0 + c);
  dst[0] = *(uint4*)(&tmp[0]);
  dst[1] = *(uint4*)(&tmp[8]);
}

// ---------- fused causal attention (swapped-QK^T layout) ----------
// grid (16 qtiles, 32 bh); block 256 = 4 waves; each wave owns 32 q-rows.
// mfma(K,Q): C col = q-row (lane&15 + qf2*16), C row = k-col (g*4+reg).
// Lane holds 4 CONSECUTIVE k columns of one q-row -> float4 attn stores,
// ds_write_b64 P staging (XOR-swizzled), 2-shfl row reductions.
__global__ __launch_bounds__(256) void attn_kernel(const u16* __restrict__ Qp,
                                                   const u16* __restrict__ Kp,
                                                   const u16* __restrict__ Vt,
                                                   float* __restrict__ attn_all,
                                                   u16* __restrict__ ctx) {
  __shared__ __align__(16) u16 Plds[4 * 32 * 128];   // 8KB per wave, swizzled
  const int tid = threadIdx.x;
  const int wave = tid >> 6, lane = tid & 63;
  const int g = lane >> 4, l16 = lane & 15;
  const int qt = (int)gridDim.x - 1 - blockIdx.x;    // heavy tiles dispatch first
  const int bh = blockIdx.y;
  const int b = bh >> 3, h = bh & 7;
  const int q0 = qt * 128;
  const int wq = q0 + wave * 32;
  const u16* Qh = Qp + (size_t)b * 2048 * 512 + h * 64;
  const u16* Kh = Kp + (size_t)b * 2048 * 512 + h * 64;
  const u16* Vh = Vt + ((size_t)b * 512 + h * 64) * 2048;
  float* attn = attn_all + (size_t)bh * 2048 * 2048;
  char* Pw = (char*)Plds + wave * 8192;
  const int swk = (l16 & 7) << 4;                    // XOR swizzle key (row&7)<<4

  // Q fragments (B-operand: col=q-row=lane&15, k=(lane>>4)*8+j)
  bf16x8 qf[2][2];
#pragma unroll
  for (int qf2 = 0; qf2 < 2; ++qf2)
#pragma unroll
    for (int kb = 0; kb < 2; ++kb)
      qf[qf2][kb] = *(const bf16x8*)(Qh + (size_t)(wq + qf2 * 16 + l16) * 512 + kb * 32 + g * 8);

  const int qrow[2] = {wq + l16, wq + 16 + l16};
  float m[2] = {-1e30f, -1e30f}, l[2] = {0.f, 0.f};
  const int nkt = qt + 1;

  // ---- Pass A: row max & sum ----
  for (int kt = 0; kt < nkt; ++kt) {
    const int ktb = kt * 128;
    float s[2][8][4];
#pragma unroll
    for (int kf = 0; kf < 8; ++kf) {
      const u16* Krow = Kh + (size_t)(ktb + kf * 16 + l16) * 512;
      bf16x8 k0 = *(const bf16x8*)(Krow + g * 8);
      bf16x8 k1 = *(const bf16x8*)(Krow + 32 + g * 8);
#pragma unroll
      for (int qf2 = 0; qf2 < 2; ++qf2) {
        f32x4 cacc = {0.f, 0.f, 0.f, 0.f};
        __builtin_amdgcn_s_setprio(1);
        cacc = MFMA_B16(k0, qf[qf2][0], cacc);
        cacc = MFMA_B16(k1, qf[qf2][1], cacc);
        __builtin_amdgcn_s_setprio(0);
        const int kbase = ktb + kf * 16 + g * 4;
#pragma unroll
        for (int r = 0; r < 4; ++r)
          s[qf2][kf][r] = (kbase + r > qrow[qf2]) ? -1e30f : cacc[r] * 0.125f;
      }
    }
#pragma unroll
    for (int qf2 = 0; qf2 < 2; ++qf2) {
      float pm = s[qf2][0][0];
#pragma unroll
      for (int kf = 0; kf < 8; ++kf)
#pragma unroll
        for (int r = 0; r < 4; ++r) pm = fmaxf(pm, s[qf2][kf][r]);
      pm = fmaxf(pm, __shfl_xor(pm, 16));
      pm = fmaxf(pm, __shfl_xor(pm, 32));
      float mn = fmaxf(m[qf2], pm);
      float ps = 0.f;
#pragma unroll
      for (int kf = 0; kf < 8; ++kf)
#pragma unroll
        for (int r = 0; r < 4; ++r) ps += __expf(s[qf2][kf][r] - mn);
      ps += __shfl_xor(ps, 16);
      ps += __shfl_xor(ps, 32);
      l[qf2] = l[qf2] * __expf(m[qf2] - mn) + ps;
      m[qf2] = mn;
    }
  }

  const float invl[2] = {1.f / l[0], 1.f / l[1]};

  // ---- Pass B: write attn (float4) + PV ----
  f32x4 oacc[2][4] = {};
  for (int kt = 0; kt < nkt; ++kt) {
    const int ktb = kt * 128;
#pragma unroll
    for (int kf = 0; kf < 8; ++kf) {
      const u16* Krow = Kh + (size_t)(ktb + kf * 16 + l16) * 512;
      bf16x8 k0 = *(const bf16x8*)(Krow + g * 8);
      bf16x8 k1 = *(const bf16x8*)(Krow + 32 + g * 8);
#pragma unroll
      for (int qf2 = 0; qf2 < 2; ++qf2) {
        f32x4 cacc = {0.f, 0.f, 0.f, 0.f};
        __builtin_amdgcn_s_setprio(1);
        cacc = MFMA_B16(k0, qf[qf2][0], cacc);
        cacc = MFMA_B16(k1, qf[qf2][1], cacc);
        __builtin_amdgcn_s_setprio(0);
        const int kbase = ktb + kf * 16 + g * 4;
        float4 p;
        p.x = (kbase + 0 > qrow[qf2]) ? 0.f : __expf(cacc[0] * 0.125f - m[qf2]) * invl[qf2];
        p.y = (kbase + 1 > qrow[qf2]) ? 0.f : __expf(cacc[1] * 0.125f - m[qf2]) * invl[qf2];
        p.z = (kbase + 2 > qrow[qf2]) ? 0.f : __expf(cacc[2] * 0.125f - m[qf2]) * invl[qf2];
        p.w = (kbase + 3 > qrow[qf2]) ? 0.f : __expf(cacc[3] * 0.125f - m[qf2]) * invl[qf2];
        *(float4*)(&attn[(size_t)qrow[qf2] * 2048 + kbase]) = p;
        unsigned int lo = (unsigned)f2bf(p.x) | ((unsigned)f2bf(p.y) << 16);
        unsigned int hi = (unsigned)f2bf(p.z) | ((unsigned)f2bf(p.w) << 16);
        *(uint2*)(Pw + (qf2 * 16 + l16) * 256 + ((kf * 32 + g * 8) ^ swk)) = make_uint2(lo, hi);
      }
    }
    asm volatile("s_waitcnt lgkmcnt(0)" ::: "memory");
    __builtin_amdgcn_sched_barrier(0);
#pragma unroll
    for (int kb = 0; kb < 4; ++kb) {
      bf16x8 pa[2];
#pragma unroll
      for (int fr = 0; fr < 2; ++fr)
        pa[fr] = *(const bf16x8*)(Pw + (fr * 16 + l16) * 256 + ((kb * 64 + g * 16) ^ swk));
#pragma unroll
      for (int cn = 0; cn < 4; ++cn) {
        bf16x8 vb = *(const bf16x8*)(Vh + (size_t)(cn * 16 + l16) * 2048 + ktb + kb * 32 + g * 8);
        __builtin_amdgcn_s_setprio(1);
#pragma unroll
        for (int fr = 0; fr < 2; ++fr)
          oacc[fr][cn] = MFMA_B16(pa[fr], vb, oacc[fr][cn]);
        __builtin_amdgcn_s_setprio(0);
      }
    }
    asm volatile("s_waitcnt lgkmcnt(0)" ::: "memory");
    __builtin_amdgcn_sched_barrier(0);
  }

  // ctx write: [B,S,D] bf16 (C layout: row=q=g*4+r within fr*16, col=d=l16)
  u16* cb = ctx + (size_t)b * 2048 * 512 + h * 64;
#pragma unroll
  for (int fr = 0; fr < 2; ++fr)
#pragma unroll
    for (int cn = 0; cn < 4; ++cn)
#pragma unroll
      for (int r = 0; r < 4; ++r)
        cb[(size_t)(wq + fr * 16 + g * 4 + r) * 512 + cn * 16 + l16] = f2bf(oacc[fr][cn][r]);

  // zero fill strictly-upper tail columns
  const int z0 = nkt * 128;
  const int zw = 2048 - z0;
  if (zw > 0) {
    const int cpr = zw >> 2;
    const int total = 128 * cpr;
    float4 z4 = make_float4(0.f, 0.f, 0.f, 0.f);
    for (int idx = tid; idx < total; idx += 256) {
      int r = idx / cpr;
      int c = (idx - r * cpr) * 4;
      *(float4*)(&attn[(size_t)(q0 + r) * 2048 + z0 + c]) = z4;
    }
  }
}

// ---------- residual + LayerNorm ----------
__global__ __launch_bounds__(256) void ln_kernel(const float* __restrict__ proj,
                                                 const float* __restrict__ resid,
                                                 const float* __restrict__ gamma,
                                                 const float* __restrict__ beta,
                                                 float* __restrict__ out) {
  const int wave = threadIdx.x >> 6, lane = threadIdx.x & 63;
  const int row = blockIdx.x * 4 + wave;
  const float4* p4 = (const float4*)(proj + (size_t)row * 512);
  const float4* r4 = (const float4*)(resid + (size_t)row * 512);
  float4 a0 = p4[lane * 2], a1 = p4[lane * 2 + 1];
  float4 q0 = r4[lane * 2], q1 = r4[lane * 2 + 1];
  float x[8];
  x[0] = a0.x + q0.x; x[1] = a0.y + q0.y; x[2] = a0.z + q0.z; x[3] = a0.w + q0.w;
  x[4] = a1.x + q1.x; x[5] = a1.y + q1.y; x[6] = a1.z + q1.z; x[7] = a1.w + q1.w;
  float s = 0.f;
#pragma unroll
  for (int j = 0; j < 8; ++j) s += x[j];
#pragma unroll
  for (int d = 1; d < 64; d <<= 1) s += __shfl_xor(s, d);
  float mu = s * (1.f / 512.f);
  float v = 0.f;
#pragma unroll
  for (int j = 0; j < 8; ++j) { float t = x[j] - mu; v += t * t; }
#pragma unroll
  for (int d = 1; d < 64; d <<= 1) v += __shfl_xor(v, d);
  float rs = rsqrtf(v * (1.f / 512.f) + 1e-5f);
  const float4* g4 = (const float4*)gamma;
  const float4* b4 = (const float4*)beta;
  float4 g0 = g4[lane * 2], g1 = g4[lane * 2 + 1];
  float4 bb0 = b4[lane * 2], bb1 = b4[lane * 2 + 1];
  float4 y0, y1;
  y0.x = (x[0] - mu) * rs * g0.x + bb0.x;
  y0.y = (x[1] - mu) * rs * g0.y + bb0.y;
  y0.z = (x[2] - mu) * rs * g0.z + bb0.z;
  y0.w = (x[3] - mu) * rs * g0.w + bb0.w;
  y1.x = (x[4] - mu) * rs * g1.x + bb1.x;
  y1.y = (x[5] - mu) * rs * g1.y + bb1.y;
  y1.z = (x[6] - mu) * rs * g1.z + bb1.z;
  y1.w = (x[7] - mu) * rs * g1.w + bb1.w;
  float4* o4 = (float4*)(out + (size_t)row * 512);
  o4[lane * 2] = y0;
  o4[lane * 2 + 1] = y1;
}

// ---------- launch ----------
extern "C" void kernel_launch(void* const* d_in, const int* in_sizes, int n_in,
                              void* d_out, int out_size, void* d_ws, size_t ws_size,
                              hipStream_t stream) {
  (void)in_sizes; (void)n_in; (void)out_size; (void)ws_size;
  const float* inQ = (const float*)d_in[0];
  const float* inK = (const float*)d_in[1];
  const float* inV = (const float*)d_in[2];
  const float* Wq = (const float*)d_in[4];
  const float* Wk = (const float*)d_in[5];
  const float* Wv = (const float*)d_in[6];
  const float* Wo = (const float*)d_in[7];
  const float* gamma = (const float*)d_in[8];
  const float* beta = (const float*)d_in[9];

  float* out = (float*)d_out;
  float* attn = out + (size_t)4 * 2048 * 512;

  char* ws = (char*)d_ws;
  u16* Qp  = (u16*)(ws + 0);
  u16* Kp  = (u16*)(ws + 8388608);
  u16* Vp  = (u16*)(ws + 16777216);
  u16* Vt  = (u16*)(ws + 25165824);
  u16* ctx = (u16*)(ws + 33554432);
  u16* Wbf = (u16*)(ws + 41943040);
  float* proj = (float*)(ws + 0);
  u16* Xbf = (u16*)attn;

  cvt3<<<2048, 256, 0, stream>>>(inQ, inK, inV, Xbf, 1048576, 4194304);
  cvtW<<<256, 256, 0, stream>>>(Wq, Wk, Wv, Wo, Wbf, 65536, 262144);
  gemm_qkv<<<dim3(64, 4, 3), 256, 0, stream>>>(Xbf, Wbf, Qp);
  transpose_v<<<dim3(32, 8, 4), 256, 0, stream>>>(Vp, Vt);
  attn_kernel<<<dim3(16, 32), 256, 0, stream>>>(Qp, Kp, Vt, attn, ctx);
  gemm_f32out<<<dim3(64, 4, 1), 256, 0, stream>>>(ctx, Wbf + (size_t)3 * 262144, proj);
  ln_kernel<<<2048, 256, 0, stream>>>(proj, inQ, gamma, beta, out);
}